// Round 5
// baseline (375.057 us; speedup 1.0000x reference)
//
#include <hip/hip_runtime.h>

#define N_NODES 50000
#define N_EDGES 800000
#define SCAN_BLOCKS 196          // ceil(50000/256)
#define WIN 6250                 // dst window per XCD group (50000/8)

typedef __attribute__((ext_vector_type(8))) short short8;
typedef __attribute__((ext_vector_type(4))) float f32x4;
typedef unsigned short ushort_t;
typedef unsigned int uint_t;

// ---------------- helpers ----------------
__device__ inline ushort_t f2bf(float f) {
    union { float f; uint_t u; } v; v.f = f;
    uint_t u = v.u;
    u += 0x7fffu + ((u >> 16) & 1u);   // RNE
    return (ushort_t)(u >> 16);
}
__device__ inline float bflo(uint_t v) { return __uint_as_float(v << 16); }
__device__ inline float bfhi(uint_t v) { return __uint_as_float(v & 0xffff0000u); }
__device__ inline float bf2f(ushort_t v) { return __uint_as_float((uint_t)v << 16); }

// ---------------- prep: cvt x->bf16, pack 3 weight sets, zero cnt ----------------
// pack order: elem (ks,t,lane,j) -> ((ks*8+t)*64+lane)*8+j; B[n][k]: n=t*16+(l&15),
// k=ks*32+(l>>4)*8+j. One wave's (ks,t) fragment = contiguous 1KB.
__global__ void prep(const float* __restrict__ x, uint_t* __restrict__ x_bf_u,
                     const float* __restrict__ Wl0, const float* __restrict__ Wr0,
                     const float* __restrict__ Wl1, const float* __restrict__ Wr1,
                     const float* __restrict__ Wl2, const float* __restrict__ Wr2,
                     ushort_t* __restrict__ pk0, ushort_t* __restrict__ pk1,
                     ushort_t* __restrict__ pkz, int* __restrict__ cnt) {
    int b = blockIdx.x, tid = threadIdx.x;
    if (b < 6250) {                                    // cvt: 1.6M ushort4
        int i = b * 256 + tid;
        float4 v = ((const float4*)x)[i];
        uint_t lo = (uint_t)f2bf(v.x) | ((uint_t)f2bf(v.y) << 16);
        uint_t hi = (uint_t)f2bf(v.z) | ((uint_t)f2bf(v.w) << 16);
        x_bf_u[i * 2] = lo; x_bf_u[i * 2 + 1] = hi;
    } else if (b < 6506) {                             // pack pk0 / pk1 (32768 each)
        int bb = b - 6250;
        const float* Wl = (bb < 128) ? Wl0 : Wl1;
        const float* Wr = (bb < 128) ? Wr0 : Wr1;
        ushort_t* out = (bb < 128) ? pk0 : pk1;
        int idx = (bb & 127) * 256 + tid;
        int j = idx & 7, l = (idx >> 3) & 63, t = (idx >> 9) & 7, ks = idx >> 12;
        int n = t * 16 + (l & 15);
        int k = ks * 32 + (l >> 4) * 8 + j;
        float w = (k < 128) ? Wl[k * 128 + n] : Wr[(k - 128) * 128 + n];
        out[idx] = f2bf(w);
    } else if (b < 6570) {                             // pack pkz (16384)
        int idx = (b - 6506) * 256 + tid;
        int j = idx & 7, l = (idx >> 3) & 63, t = (idx >> 9) & 7, ks = idx >> 12;
        int n = t * 16 + (l & 15);
        int k = ks * 32 + (l >> 4) * 8 + j;
        float w = (n < 64) ? Wl2[k * 64 + n] : Wr2[k * 64 + (n - 64)];
        pkz[idx] = f2bf(w);
    } else {                                           // zero cnt: 12500 int4
        int i = (b - 6570) * 256 + tid;
        if (i < 12500) ((int4*)cnt)[i] = make_int4(0, 0, 0, 0);
    }
}

// ---------------- CSR build: XCD-windowed counting sort ----------------
__global__ void count_edges_mp(const int* __restrict__ ei, int* __restrict__ cnt) {
    int g = blockIdx.x & 7;
    int nb = gridDim.x >> 3;
    int bi = blockIdx.x >> 3;
    int lo = g * WIN;
    for (int e = bi * 256 + threadIdx.x; e < N_EDGES; e += nb * 256) {
        int d = ei[N_EDGES + e];
        if ((unsigned)(d - lo) < WIN) atomicAdd(&cnt[d], 1);
    }
}

__global__ void fill_csr_mp(const int* __restrict__ ei, int* __restrict__ cursor,
                            int* __restrict__ csr_src) {
    int g = blockIdx.x & 7;
    int nb = gridDim.x >> 3;
    int bi = blockIdx.x >> 3;
    int lo = g * WIN;
    for (int e = bi * 256 + threadIdx.x; e < N_EDGES; e += nb * 256) {
        int d = ei[N_EDGES + e];
        if ((unsigned)(d - lo) < WIN) {
            int p = atomicAdd(&cursor[d], 1);
            csr_src[p] = ei[e];
        }
    }
}

__global__ void block_sums(const int* __restrict__ cnt, int* __restrict__ bsum) {
    int i = blockIdx.x * 256 + threadIdx.x;
    int v = (i < N_NODES) ? cnt[i] : 0;
    for (int off = 32; off; off >>= 1) v += __shfl_down(v, off, 64);
    __shared__ int s[4];
    if ((threadIdx.x & 63) == 0) s[threadIdx.x >> 6] = v;
    __syncthreads();
    if (threadIdx.x == 0) bsum[blockIdx.x] = s[0] + s[1] + s[2] + s[3];
}

__global__ void scan_bsums(const int* __restrict__ bsum, int* __restrict__ bprefix,
                           int* __restrict__ rowstart) {
    __shared__ int s[256];
    int t = threadIdx.x;
    int v = (t < SCAN_BLOCKS) ? bsum[t] : 0;
    s[t] = v;
    __syncthreads();
    for (int off = 1; off < 256; off <<= 1) {
        int add = (t >= off) ? s[t - off] : 0;
        __syncthreads();
        s[t] += add;
        __syncthreads();
    }
    bprefix[t] = s[t] - v;
    if (t == 0) rowstart[N_NODES] = N_EDGES;
}

__global__ void apply_scan(const int* __restrict__ cnt, const int* __restrict__ bprefix,
                           int* __restrict__ rowstart, int* __restrict__ cursor) {
    __shared__ int s[256];
    int t = threadIdx.x;
    int i = blockIdx.x * 256 + t;
    int v = (i < N_NODES) ? cnt[i] : 0;
    s[t] = v;
    __syncthreads();
    for (int off = 1; off < 256; off <<= 1) {
        int add = (t >= off) ? s[t - off] : 0;
        __syncthreads();
        s[t] += add;
        __syncthreads();
    }
    int excl = s[t] - v + bprefix[blockIdx.x];
    if (i < N_NODES) { rowstart[i] = excl; cursor[i] = excl; }
}

// ---------------- gather helper: mean of neighbor rows -> (ax, ay) ----------------
__device__ inline void gather_mean(const uint_t* __restrict__ base,
                                   const int* __restrict__ rowstart,
                                   const int* __restrict__ csr_src,
                                   int node, int lane, float& ax, float& ay) {
    int s0 = rowstart[node], s1 = rowstart[node + 1];
    ax = 0.f; ay = 0.f;
    for (int b = s0; b < s1; b += 64) {
        int m = min(64, s1 - b);
        int idx = (lane < m) ? csr_src[b + lane] : 0;
        int j = 0;
        for (; j + 8 <= m; j += 8) {
            uint_t v0 = base[(size_t)__shfl(idx, j + 0, 64) * 64 + lane];
            uint_t v1 = base[(size_t)__shfl(idx, j + 1, 64) * 64 + lane];
            uint_t v2 = base[(size_t)__shfl(idx, j + 2, 64) * 64 + lane];
            uint_t v3 = base[(size_t)__shfl(idx, j + 3, 64) * 64 + lane];
            uint_t v4 = base[(size_t)__shfl(idx, j + 4, 64) * 64 + lane];
            uint_t v5 = base[(size_t)__shfl(idx, j + 5, 64) * 64 + lane];
            uint_t v6 = base[(size_t)__shfl(idx, j + 6, 64) * 64 + lane];
            uint_t v7 = base[(size_t)__shfl(idx, j + 7, 64) * 64 + lane];
            ax += ((bflo(v0) + bflo(v1)) + (bflo(v2) + bflo(v3)))
                + ((bflo(v4) + bflo(v5)) + (bflo(v6) + bflo(v7)));
            ay += ((bfhi(v0) + bfhi(v1)) + (bfhi(v2) + bfhi(v3)))
                + ((bfhi(v4) + bfhi(v5)) + (bfhi(v6) + bfhi(v7)));
        }
        for (; j < m; ++j) {
            uint_t v = base[(size_t)__shfl(idx, j, 64) * 64 + lane];
            ax += bflo(v);
            ay += bfhi(v);
        }
    }
    float inv = 1.0f / fmaxf((float)(s1 - s0), 1.0f);
    ax *= inv; ay *= inv;
}

// ---------------- layer 0 fused: gather(x) + MFMA -> h1 = relu([mean|x]@pk0 + b0) ----------------
// Wave owns 16 nodes. Mean tile in per-wave LDS [16][136] bf16 (272B stride, 16B-aligned frags).
__global__ __launch_bounds__(256) void layer0_fused(
    const uint_t* __restrict__ xg, const ushort_t* __restrict__ x_root,
    const int* __restrict__ rowstart, const int* __restrict__ csr_src,
    const ushort_t* __restrict__ Bpk, const float* __restrict__ bias,
    ushort_t* __restrict__ h1) {
    __shared__ ushort_t Ash[4][16 * 136];
    int lane = threadIdx.x & 63, wave = threadIdx.x >> 6;
    ushort_t* my = Ash[wave];
    int nodeBase = blockIdx.x * 64 + wave * 16;

    for (int m = 0; m < 16; ++m) {
        int node = nodeBase + m;
        float ax = 0.f, ay = 0.f;
        if (node < N_NODES) gather_mean(xg, rowstart, csr_src, node, lane, ax, ay);
        uint_t packed = (uint_t)f2bf(ax) | ((uint_t)f2bf(ay) << 16);
        ((uint_t*)(my + m * 136))[lane] = packed;
    }

    int row16 = lane & 15, quad = lane >> 4;
    const short8* bp = (const short8*)Bpk + lane;
    int rootRow = min(nodeBase + row16, N_NODES - 1);
    const ushort_t* rrow = x_root + (size_t)rootRow * 128;

    f32x4 acc[8];
    #pragma unroll
    for (int t = 0; t < 8; ++t) { f32x4 z = {0.f, 0.f, 0.f, 0.f}; acc[t] = z; }

    #pragma unroll
    for (int ks = 0; ks < 8; ++ks) {
        short8 afrag;
        if (ks < 4) afrag = *(const short8*)&my[row16 * 136 + ks * 32 + quad * 8];
        else        afrag = *(const short8*)(rrow + (ks - 4) * 32 + quad * 8);
        #pragma unroll
        for (int t = 0; t < 8; ++t) {
            short8 bfrag = bp[(ks * 8 + t) * 64];
            acc[t] = __builtin_amdgcn_mfma_f32_16x16x32_bf16(afrag, bfrag, acc[t], 0, 0, 0);
        }
    }

    #pragma unroll
    for (int t = 0; t < 8; ++t) {
        int col = t * 16 + row16;
        float bv = bias[col];
        #pragma unroll
        for (int r = 0; r < 4; ++r) {
            int row = nodeBase + quad * 4 + r;
            if (row < N_NODES) {
                float v = fmaxf(acc[t][r] + bv, 0.f);
                h1[(size_t)row * 128 + col] = f2bf(v);
            }
        }
    }
}

// ---------------- layer 1+2 fused: gather(h1) + MFMA -> h2 (LDS only) -> [z|r] ----------------
__global__ __launch_bounds__(256) void layer12_fused(
    const uint_t* __restrict__ h1g, const ushort_t* __restrict__ h1_root,
    const int* __restrict__ rowstart, const int* __restrict__ csr_src,
    const ushort_t* __restrict__ Bpk1, const float* __restrict__ bias1,
    const ushort_t* __restrict__ Bpkz, const float* __restrict__ bias2,
    ushort_t* __restrict__ z_bf, float* __restrict__ r_f32) {
    __shared__ ushort_t Ash[4][16 * 136];
    int lane = threadIdx.x & 63, wave = threadIdx.x >> 6;
    ushort_t* my = Ash[wave];
    int nodeBase = blockIdx.x * 64 + wave * 16;

    for (int m = 0; m < 16; ++m) {
        int node = nodeBase + m;
        float ax = 0.f, ay = 0.f;
        if (node < N_NODES) gather_mean(h1g, rowstart, csr_src, node, lane, ax, ay);
        uint_t packed = (uint_t)f2bf(ax) | ((uint_t)f2bf(ay) << 16);
        ((uint_t*)(my + m * 136))[lane] = packed;
    }

    int row16 = lane & 15, quad = lane >> 4;
    const short8* bp = (const short8*)Bpk1 + lane;
    int rootRow = min(nodeBase + row16, N_NODES - 1);
    const ushort_t* rrow = h1_root + (size_t)rootRow * 128;

    f32x4 acc[8];
    #pragma unroll
    for (int t = 0; t < 8; ++t) { f32x4 z = {0.f, 0.f, 0.f, 0.f}; acc[t] = z; }

    #pragma unroll
    for (int ks = 0; ks < 8; ++ks) {
        short8 afrag;
        if (ks < 4) afrag = *(const short8*)&my[row16 * 136 + ks * 32 + quad * 8];
        else        afrag = *(const short8*)(rrow + (ks - 4) * 32 + quad * 8);
        #pragma unroll
        for (int t = 0; t < 8; ++t) {
            short8 bfrag = bp[(ks * 8 + t) * 64];
            acc[t] = __builtin_amdgcn_mfma_f32_16x16x32_bf16(afrag, bfrag, acc[t], 0, 0, 0);
        }
    }

    // h2 = relu(acc + b1) -> LDS tile (reuse mean region; GEMM1 reads are done)
    // C layout: elem(row = quad*4+r, col = t*16+row16)
    #pragma unroll
    for (int t = 0; t < 8; ++t) {
        int col = t * 16 + row16;
        float bv = bias1[col];
        #pragma unroll
        for (int r = 0; r < 4; ++r) {
            float v = fmaxf(acc[t][r] + bv, 0.f);
            my[(quad * 4 + r) * 136 + col] = f2bf(v);
        }
    }

    // GEMM2: [z|r] = h2 @ pkz (K=128)
    const short8* bpz = (const short8*)Bpkz + lane;
    f32x4 accz[8];
    #pragma unroll
    for (int t = 0; t < 8; ++t) { f32x4 z = {0.f, 0.f, 0.f, 0.f}; accz[t] = z; }

    #pragma unroll
    for (int ks = 0; ks < 4; ++ks) {
        short8 afrag = *(const short8*)&my[row16 * 136 + ks * 32 + quad * 8];
        #pragma unroll
        for (int t = 0; t < 8; ++t) {
            short8 bfrag = bpz[(ks * 8 + t) * 64];
            accz[t] = __builtin_amdgcn_mfma_f32_16x16x32_bf16(afrag, bfrag, accz[t], 0, 0, 0);
        }
    }

    #pragma unroll
    for (int t = 0; t < 8; ++t) {
        int col = t * 16 + row16;
        #pragma unroll
        for (int r = 0; r < 4; ++r) {
            int row = nodeBase + quad * 4 + r;
            if (row < N_NODES) {
                if (col < 64) z_bf[(size_t)row * 64 + col] = f2bf(accz[t][r]);
                else          r_f32[(size_t)row * 64 + (col - 64)] = accz[t][r] + bias2[col - 64];
            }
        }
    }
}

// ---------------- final: mean(z[src]) + r, log_softmax, write both outputs ----------------
__global__ void final_agg_softmax(const ushort_t* __restrict__ z_bf,
                                  const float* __restrict__ r_f32,
                                  const int* __restrict__ rowstart,
                                  const int* __restrict__ csr_src,
                                  float* __restrict__ out) {
    int node = blockIdx.x * 4 + (threadIdx.x >> 6);
    int lane = threadIdx.x & 63;
    if (node >= N_NODES) return;
    int s0 = rowstart[node], s1 = rowstart[node + 1];
    float a = 0.f;
    for (int b = s0; b < s1; b += 64) {
        int m = min(64, s1 - b);
        int idx = (lane < m) ? csr_src[b + lane] : 0;
        int j = 0;
        for (; j + 8 <= m; j += 8) {
            float v0 = bf2f(z_bf[(size_t)__shfl(idx, j + 0, 64) * 64 + lane]);
            float v1 = bf2f(z_bf[(size_t)__shfl(idx, j + 1, 64) * 64 + lane]);
            float v2 = bf2f(z_bf[(size_t)__shfl(idx, j + 2, 64) * 64 + lane]);
            float v3 = bf2f(z_bf[(size_t)__shfl(idx, j + 3, 64) * 64 + lane]);
            float v4 = bf2f(z_bf[(size_t)__shfl(idx, j + 4, 64) * 64 + lane]);
            float v5 = bf2f(z_bf[(size_t)__shfl(idx, j + 5, 64) * 64 + lane]);
            float v6 = bf2f(z_bf[(size_t)__shfl(idx, j + 6, 64) * 64 + lane]);
            float v7 = bf2f(z_bf[(size_t)__shfl(idx, j + 7, 64) * 64 + lane]);
            a += ((v0 + v1) + (v2 + v3)) + ((v4 + v5) + (v6 + v7));
        }
        for (; j < m; ++j)
            a += bf2f(z_bf[(size_t)__shfl(idx, j, 64) * 64 + lane]);
    }
    float inv = 1.0f / fmaxf((float)(s1 - s0), 1.0f);
    float h = a * inv + r_f32[(size_t)node * 64 + lane];
    float mx = h;
    for (int off = 32; off; off >>= 1) mx = fmaxf(mx, __shfl_xor(mx, off, 64));
    float e = expf(h - mx);
    float s = e;
    for (int off = 32; off; off >>= 1) s += __shfl_xor(s, off, 64);
    float lse = mx + logf(s);
    out[(size_t)node * 64 + lane] = h - lse;                               // log_softmax
    out[(size_t)N_NODES * 64 + (size_t)node * 64 + lane] = h;              // h
}

extern "C" void kernel_launch(void* const* d_in, const int* in_sizes, int n_in,
                              void* d_out, int out_size, void* d_ws, size_t ws_size,
                              hipStream_t stream) {
    const float* x  = (const float*)d_in[0];
    const int* ei   = (const int*)d_in[1];
    const float* Wl0 = (const float*)d_in[2];
    const float* Wr0 = (const float*)d_in[3];
    const float* b0  = (const float*)d_in[4];
    const float* Wl1 = (const float*)d_in[5];
    const float* Wr1 = (const float*)d_in[6];
    const float* b1  = (const float*)d_in[7];
    const float* Wl2 = (const float*)d_in[8];
    const float* Wr2 = (const float*)d_in[9];
    const float* b2  = (const float*)d_in[10];
    float* out = (float*)d_out;

    char* ws = (char*)d_ws;
    int* cnt      = (int*)(ws + 0x000000);
    int* rowstart = (int*)(ws + 0x040000);
    int* cursor   = (int*)(ws + 0x080000);
    int* bsum     = (int*)(ws + 0x0C0000);
    int* bprefix  = (int*)(ws + 0x0C1000);
    int* csr_src  = (int*)(ws + 0x100000);            // 3.2 MB
    ushort_t* pk0 = (ushort_t*)(ws + 0x420000);       // 64 KB
    ushort_t* pk1 = (ushort_t*)(ws + 0x440000);       // 64 KB
    ushort_t* pkz = (ushort_t*)(ws + 0x460000);       // 32 KB
    ushort_t* x_bf = (ushort_t*)(ws + 0x0500000);     // 12.8 MB; dead after layer0
    ushort_t* h1   = (ushort_t*)(ws + 0x1F00000);     // 12.8 MB
    ushort_t* z_bf = (ushort_t*)(ws + 0x1200000);     // 6.4 MB
    float*    r_f32 = (float*)  (ws + 0x0500000);     // 12.8 MB, aliases x_bf (dead)

    // ---- prep: cvt + weight packs + zero cnt (one kernel) ----
    prep<<<6619, 256, 0, stream>>>(x, (uint_t*)x_bf, Wl0, Wr0, Wl1, Wr1, Wl2, Wr2,
                                   pk0, pk1, pkz, cnt);

    // ---- CSR build (XCD-windowed counting sort) ----
    count_edges_mp<<<1024, 256, 0, stream>>>(ei, cnt);
    block_sums<<<SCAN_BLOCKS, 256, 0, stream>>>(cnt, bsum);
    scan_bsums<<<1, 256, 0, stream>>>(bsum, bprefix, rowstart);
    apply_scan<<<SCAN_BLOCKS, 256, 0, stream>>>(cnt, bprefix, rowstart, cursor);
    fill_csr_mp<<<1024, 256, 0, stream>>>(ei, cursor, csr_src);

    // ---- layer 0 fused: x -> h1 ----
    layer0_fused<<<782, 256, 0, stream>>>((const uint_t*)x_bf, x_bf, rowstart, csr_src,
                                          pk0, b0, h1);

    // ---- layers 1+2 fused: h1 -> (z, r); h2 never leaves LDS ----
    layer12_fused<<<782, 256, 0, stream>>>((const uint_t*)h1, h1, rowstart, csr_src,
                                           pk1, b1, pkz, b2, z_bf, r_f32);

    // ---- final gather + log_softmax -> d_out ----
    final_agg_softmax<<<12500, 256, 0, stream>>>(z_bf, r_f32, rowstart, csr_src, out);
}

// Round 6
// 330.931 us; speedup vs baseline: 1.1333x; 1.1333x over previous
//
#include <hip/hip_runtime.h>

#define N_NODES 50000
#define N_EDGES 800000
#define SCAN_BLOCKS 196          // ceil(50000/256)
#define WIN 6250                 // dst window per XCD group (50000/8)

typedef __attribute__((ext_vector_type(8))) short short8;
typedef __attribute__((ext_vector_type(4))) float f32x4;
typedef unsigned short ushort_t;
typedef unsigned int uint_t;

// ---------------- helpers ----------------
__device__ inline ushort_t f2bf(float f) {
    union { float f; uint_t u; } v; v.f = f;
    uint_t u = v.u;
    u += 0x7fffu + ((u >> 16) & 1u);   // RNE
    return (ushort_t)(u >> 16);
}
__device__ inline float bflo(uint_t v) { return __uint_as_float(v << 16); }
__device__ inline float bfhi(uint_t v) { return __uint_as_float(v & 0xffff0000u); }
__device__ inline float bf2f(ushort_t v) { return __uint_as_float((uint_t)v << 16); }

// ---------------- prep: cvt x->bf16, pack 3 weight sets, zero cnt ----------------
__global__ void prep(const float* __restrict__ x, uint_t* __restrict__ x_bf_u,
                     const float* __restrict__ Wl0, const float* __restrict__ Wr0,
                     const float* __restrict__ Wl1, const float* __restrict__ Wr1,
                     const float* __restrict__ Wl2, const float* __restrict__ Wr2,
                     ushort_t* __restrict__ pk0, ushort_t* __restrict__ pk1,
                     ushort_t* __restrict__ pkz, int* __restrict__ cnt) {
    int b = blockIdx.x, tid = threadIdx.x;
    if (b < 6250) {                                    // cvt: 1.6M ushort4
        int i = b * 256 + tid;
        float4 v = ((const float4*)x)[i];
        uint_t lo = (uint_t)f2bf(v.x) | ((uint_t)f2bf(v.y) << 16);
        uint_t hi = (uint_t)f2bf(v.z) | ((uint_t)f2bf(v.w) << 16);
        x_bf_u[i * 2] = lo; x_bf_u[i * 2 + 1] = hi;
    } else if (b < 6506) {                             // pack pk0 / pk1 (32768 each)
        int bb = b - 6250;
        const float* Wl = (bb < 128) ? Wl0 : Wl1;
        const float* Wr = (bb < 128) ? Wr0 : Wr1;
        ushort_t* out = (bb < 128) ? pk0 : pk1;
        int idx = (bb & 127) * 256 + tid;
        int j = idx & 7, l = (idx >> 3) & 63, t = (idx >> 9) & 7, ks = idx >> 12;
        int n = t * 16 + (l & 15);
        int k = ks * 32 + (l >> 4) * 8 + j;
        float w = (k < 128) ? Wl[k * 128 + n] : Wr[(k - 128) * 128 + n];
        out[idx] = f2bf(w);
    } else if (b < 6570) {                             // pack pkz (16384)
        int idx = (b - 6506) * 256 + tid;
        int j = idx & 7, l = (idx >> 3) & 63, t = (idx >> 9) & 7, ks = idx >> 12;
        int n = t * 16 + (l & 15);
        int k = ks * 32 + (l >> 4) * 8 + j;
        float w = (n < 64) ? Wl2[k * 64 + n] : Wr2[k * 64 + (n - 64)];
        pkz[idx] = f2bf(w);
    } else {                                           // zero cnt: 12500 int4
        int i = (b - 6570) * 256 + tid;
        if (i < 12500) ((int4*)cnt)[i] = make_int4(0, 0, 0, 0);
    }
}

// ---------------- CSR build: XCD-windowed counting sort ----------------
__global__ void count_edges_mp(const int* __restrict__ ei, int* __restrict__ cnt) {
    int g = blockIdx.x & 7;
    int nb = gridDim.x >> 3;
    int bi = blockIdx.x >> 3;
    int lo = g * WIN;
    for (int e = bi * 256 + threadIdx.x; e < N_EDGES; e += nb * 256) {
        int d = ei[N_EDGES + e];
        if ((unsigned)(d - lo) < WIN) atomicAdd(&cnt[d], 1);
    }
}

__global__ void fill_csr_mp(const int* __restrict__ ei, int* __restrict__ cursor,
                            int* __restrict__ csr_src) {
    int g = blockIdx.x & 7;
    int nb = gridDim.x >> 3;
    int bi = blockIdx.x >> 3;
    int lo = g * WIN;
    for (int e = bi * 256 + threadIdx.x; e < N_EDGES; e += nb * 256) {
        int d = ei[N_EDGES + e];
        if ((unsigned)(d - lo) < WIN) {
            int p = atomicAdd(&cursor[d], 1);
            csr_src[p] = ei[e];
        }
    }
}

// ---------------- one-kernel exclusive scan (replaces 3-kernel chain) ----------------
// block b: prefix = sum(cnt[0 .. 256b)) by brute re-scan (L2-resident, parallel),
// then local LDS scan of its 256 counts.
__global__ void scan_all(const int* __restrict__ cnt, int* __restrict__ rowstart,
                         int* __restrict__ cursor) {
    __shared__ int s[256];
    __shared__ int wsum[4];
    int t = threadIdx.x, b = blockIdx.x;
    int base = b * 256;
    int pre = 0;
    for (int i = t; i < base; i += 256) pre += cnt[i];
    for (int off = 32; off; off >>= 1) pre += __shfl_down(pre, off, 64);
    if ((t & 63) == 0) wsum[t >> 6] = pre;
    __syncthreads();
    int prefix_base = wsum[0] + wsum[1] + wsum[2] + wsum[3];
    int i = base + t;
    int v = (i < N_NODES) ? cnt[i] : 0;
    s[t] = v;
    __syncthreads();
    for (int off = 1; off < 256; off <<= 1) {
        int add = (t >= off) ? s[t - off] : 0;
        __syncthreads();
        s[t] += add;
        __syncthreads();
    }
    int excl = s[t] - v + prefix_base;
    if (i < N_NODES) { rowstart[i] = excl; cursor[i] = excl; }
    if (b == 0 && t == 0) rowstart[N_NODES] = N_EDGES;
}

// ---------------- gather helper: mean of neighbor rows -> (ax, ay) ----------------
__device__ inline void gather_mean(const uint_t* __restrict__ base,
                                   const int* __restrict__ rowstart,
                                   const int* __restrict__ csr_src,
                                   int node, int lane, float& ax, float& ay) {
    int s0 = rowstart[node], s1 = rowstart[node + 1];
    ax = 0.f; ay = 0.f;
    for (int b = s0; b < s1; b += 64) {
        int m = min(64, s1 - b);
        int idx = (lane < m) ? csr_src[b + lane] : 0;
        int j = 0;
        for (; j + 8 <= m; j += 8) {
            uint_t v0 = base[(size_t)__shfl(idx, j + 0, 64) * 64 + lane];
            uint_t v1 = base[(size_t)__shfl(idx, j + 1, 64) * 64 + lane];
            uint_t v2 = base[(size_t)__shfl(idx, j + 2, 64) * 64 + lane];
            uint_t v3 = base[(size_t)__shfl(idx, j + 3, 64) * 64 + lane];
            uint_t v4 = base[(size_t)__shfl(idx, j + 4, 64) * 64 + lane];
            uint_t v5 = base[(size_t)__shfl(idx, j + 5, 64) * 64 + lane];
            uint_t v6 = base[(size_t)__shfl(idx, j + 6, 64) * 64 + lane];
            uint_t v7 = base[(size_t)__shfl(idx, j + 7, 64) * 64 + lane];
            ax += ((bflo(v0) + bflo(v1)) + (bflo(v2) + bflo(v3)))
                + ((bflo(v4) + bflo(v5)) + (bflo(v6) + bflo(v7)));
            ay += ((bfhi(v0) + bfhi(v1)) + (bfhi(v2) + bfhi(v3)))
                + ((bfhi(v4) + bfhi(v5)) + (bfhi(v6) + bfhi(v7)));
        }
        for (; j < m; ++j) {
            uint_t v = base[(size_t)__shfl(idx, j, 64) * 64 + lane];
            ax += bflo(v);
            ay += bfhi(v);
        }
    }
    float inv = 1.0f / fmaxf((float)(s1 - s0), 1.0f);
    ax *= inv; ay *= inv;
}

// ---------------- fused layer: 16 nodes/block, 4 waves ----------------
// gather: wave w fills LDS A-tile rows w*4..w*4+3 (4 serial node-gathers).
// MFMA: all waves share A-tile; wave w computes col-tiles t=2w,2w+1 (16x32).
// CHAIN: h2 = relu(gemm1) kept in LDS, chained into gemm2 -> [z|r].
template <bool CHAIN>
__global__ __launch_bounds__(256) void layer_fused(
    const uint_t* __restrict__ gsrc, const ushort_t* __restrict__ root,
    const int* __restrict__ rowstart, const int* __restrict__ csr_src,
    const ushort_t* __restrict__ Bpk, const float* __restrict__ bias1,
    const ushort_t* __restrict__ Bpkz, const float* __restrict__ bias2,
    ushort_t* __restrict__ h_out,
    ushort_t* __restrict__ z_bf, float* __restrict__ r_f32) {
    __shared__ ushort_t At[16 * 136];
    int lane = threadIdx.x & 63, wave = threadIdx.x >> 6;
    int nodeBase = blockIdx.x * 16;

    #pragma unroll
    for (int i = 0; i < 4; ++i) {
        int m = wave * 4 + i;
        int node = nodeBase + m;
        float ax = 0.f, ay = 0.f;
        if (node < N_NODES) gather_mean(gsrc, rowstart, csr_src, node, lane, ax, ay);
        ((uint_t*)(At + m * 136))[lane] = (uint_t)f2bf(ax) | ((uint_t)f2bf(ay) << 16);
    }
    __syncthreads();

    int row16 = lane & 15, quad = lane >> 4;
    const short8* bp = (const short8*)Bpk + lane;
    int rootRow = min(nodeBase + row16, N_NODES - 1);
    const ushort_t* rrow = root + (size_t)rootRow * 128;

    f32x4 acc[2];
    #pragma unroll
    for (int tt = 0; tt < 2; ++tt) { f32x4 z = {0.f, 0.f, 0.f, 0.f}; acc[tt] = z; }

    #pragma unroll
    for (int ks = 0; ks < 8; ++ks) {
        short8 afrag;
        if (ks < 4) afrag = *(const short8*)&At[row16 * 136 + ks * 32 + quad * 8];
        else        afrag = *(const short8*)(rrow + (ks - 4) * 32 + quad * 8);
        #pragma unroll
        for (int tt = 0; tt < 2; ++tt) {
            int t = wave * 2 + tt;
            short8 bfrag = bp[(ks * 8 + t) * 64];
            acc[tt] = __builtin_amdgcn_mfma_f32_16x16x32_bf16(afrag, bfrag, acc[tt], 0, 0, 0);
        }
    }

    if (!CHAIN) {
        #pragma unroll
        for (int tt = 0; tt < 2; ++tt) {
            int col = (wave * 2 + tt) * 16 + row16;
            float bv = bias1[col];
            #pragma unroll
            for (int r = 0; r < 4; ++r) {
                int row = nodeBase + quad * 4 + r;
                if (row < N_NODES) {
                    float v = fmaxf(acc[tt][r] + bv, 0.f);
                    h_out[(size_t)row * 128 + col] = f2bf(v);
                }
            }
        }
    } else {
        __syncthreads();   // all A-tile reads done before overwrite
        #pragma unroll
        for (int tt = 0; tt < 2; ++tt) {
            int col = (wave * 2 + tt) * 16 + row16;
            float bv = bias1[col];
            #pragma unroll
            for (int r = 0; r < 4; ++r) {
                float v = fmaxf(acc[tt][r] + bv, 0.f);
                At[(quad * 4 + r) * 136 + col] = f2bf(v);   // h2 tile
            }
        }
        __syncthreads();

        const short8* bpz = (const short8*)Bpkz + lane;
        f32x4 accz[2];
        #pragma unroll
        for (int tt = 0; tt < 2; ++tt) { f32x4 z = {0.f, 0.f, 0.f, 0.f}; accz[tt] = z; }

        #pragma unroll
        for (int ks = 0; ks < 4; ++ks) {
            short8 afrag = *(const short8*)&At[row16 * 136 + ks * 32 + quad * 8];
            #pragma unroll
            for (int tt = 0; tt < 2; ++tt) {
                int t = wave * 2 + tt;
                short8 bfrag = bpz[(ks * 8 + t) * 64];
                accz[tt] = __builtin_amdgcn_mfma_f32_16x16x32_bf16(afrag, bfrag, accz[tt], 0, 0, 0);
            }
        }

        #pragma unroll
        for (int tt = 0; tt < 2; ++tt) {
            int col = (wave * 2 + tt) * 16 + row16;
            #pragma unroll
            for (int r = 0; r < 4; ++r) {
                int row = nodeBase + quad * 4 + r;
                if (row < N_NODES) {
                    if (col < 64) z_bf[(size_t)row * 64 + col] = f2bf(accz[tt][r]);
                    else          r_f32[(size_t)row * 64 + (col - 64)] = accz[tt][r] + bias2[col - 64];
                }
            }
        }
    }
}

// ---------------- final: mean(z[src]) + r, log_softmax, write both outputs ----------------
__global__ void final_agg_softmax(const ushort_t* __restrict__ z_bf,
                                  const float* __restrict__ r_f32,
                                  const int* __restrict__ rowstart,
                                  const int* __restrict__ csr_src,
                                  float* __restrict__ out) {
    int node = blockIdx.x * 4 + (threadIdx.x >> 6);
    int lane = threadIdx.x & 63;
    if (node >= N_NODES) return;
    int s0 = rowstart[node], s1 = rowstart[node + 1];
    float a = 0.f;
    for (int b = s0; b < s1; b += 64) {
        int m = min(64, s1 - b);
        int idx = (lane < m) ? csr_src[b + lane] : 0;
        int j = 0;
        for (; j + 8 <= m; j += 8) {
            float v0 = bf2f(z_bf[(size_t)__shfl(idx, j + 0, 64) * 64 + lane]);
            float v1 = bf2f(z_bf[(size_t)__shfl(idx, j + 1, 64) * 64 + lane]);
            float v2 = bf2f(z_bf[(size_t)__shfl(idx, j + 2, 64) * 64 + lane]);
            float v3 = bf2f(z_bf[(size_t)__shfl(idx, j + 3, 64) * 64 + lane]);
            float v4 = bf2f(z_bf[(size_t)__shfl(idx, j + 4, 64) * 64 + lane]);
            float v5 = bf2f(z_bf[(size_t)__shfl(idx, j + 5, 64) * 64 + lane]);
            float v6 = bf2f(z_bf[(size_t)__shfl(idx, j + 6, 64) * 64 + lane]);
            float v7 = bf2f(z_bf[(size_t)__shfl(idx, j + 7, 64) * 64 + lane]);
            a += ((v0 + v1) + (v2 + v3)) + ((v4 + v5) + (v6 + v7));
        }
        for (; j < m; ++j)
            a += bf2f(z_bf[(size_t)__shfl(idx, j, 64) * 64 + lane]);
    }
    float inv = 1.0f / fmaxf((float)(s1 - s0), 1.0f);
    float h = a * inv + r_f32[(size_t)node * 64 + lane];
    float mx = h;
    for (int off = 32; off; off >>= 1) mx = fmaxf(mx, __shfl_xor(mx, off, 64));
    float e = expf(h - mx);
    float s = e;
    for (int off = 32; off; off >>= 1) s += __shfl_xor(s, off, 64);
    float lse = mx + logf(s);
    out[(size_t)node * 64 + lane] = h - lse;                               // log_softmax
    out[(size_t)N_NODES * 64 + (size_t)node * 64 + lane] = h;              // h
}

extern "C" void kernel_launch(void* const* d_in, const int* in_sizes, int n_in,
                              void* d_out, int out_size, void* d_ws, size_t ws_size,
                              hipStream_t stream) {
    const float* x  = (const float*)d_in[0];
    const int* ei   = (const int*)d_in[1];
    const float* Wl0 = (const float*)d_in[2];
    const float* Wr0 = (const float*)d_in[3];
    const float* b0  = (const float*)d_in[4];
    const float* Wl1 = (const float*)d_in[5];
    const float* Wr1 = (const float*)d_in[6];
    const float* b1  = (const float*)d_in[7];
    const float* Wl2 = (const float*)d_in[8];
    const float* Wr2 = (const float*)d_in[9];
    const float* b2  = (const float*)d_in[10];
    float* out = (float*)d_out;

    char* ws = (char*)d_ws;
    int* cnt      = (int*)(ws + 0x000000);
    int* rowstart = (int*)(ws + 0x040000);
    int* cursor   = (int*)(ws + 0x080000);
    int* csr_src  = (int*)(ws + 0x100000);            // 3.2 MB
    ushort_t* pk0 = (ushort_t*)(ws + 0x420000);       // 64 KB
    ushort_t* pk1 = (ushort_t*)(ws + 0x440000);       // 64 KB
    ushort_t* pkz = (ushort_t*)(ws + 0x460000);       // 32 KB
    ushort_t* x_bf = (ushort_t*)(ws + 0x0500000);     // 12.8 MB; dead after layer0
    ushort_t* h1   = (ushort_t*)(ws + 0x1F00000);     // 12.8 MB
    ushort_t* z_bf = (ushort_t*)(ws + 0x1200000);     // 6.4 MB
    float*    r_f32 = (float*)  (ws + 0x0500000);     // 12.8 MB, aliases x_bf (dead)

    // ---- prep: cvt + weight packs + zero cnt (one kernel) ----
    prep<<<6619, 256, 0, stream>>>(x, (uint_t*)x_bf, Wl0, Wr0, Wl1, Wr1, Wl2, Wr2,
                                   pk0, pk1, pkz, cnt);

    // ---- CSR build: count -> scan(1 kernel) -> fill ----
    count_edges_mp<<<1024, 256, 0, stream>>>(ei, cnt);
    scan_all<<<SCAN_BLOCKS, 256, 0, stream>>>(cnt, rowstart, cursor);
    fill_csr_mp<<<1024, 256, 0, stream>>>(ei, cursor, csr_src);

    // ---- layer 0 fused (16 nodes/block): x -> h1 ----
    layer_fused<false><<<3125, 256, 0, stream>>>(
        (const uint_t*)x_bf, x_bf, rowstart, csr_src, pk0, b0,
        nullptr, nullptr, h1, nullptr, nullptr);

    // ---- layers 1+2 fused: h1 -> (z, r); h2 never leaves LDS ----
    layer_fused<true><<<3125, 256, 0, stream>>>(
        (const uint_t*)h1, h1, rowstart, csr_src, pk1, b1,
        pkz, b2, nullptr, z_bf, r_f32);

    // ---- final gather + log_softmax -> d_out ----
    final_agg_softmax<<<12500, 256, 0, stream>>>(z_bf, r_f32, rowstart, csr_src, out);
}